// Round 4
// baseline (114.530 us; speedup 1.0000x reference)
//
#include <hip/hip_runtime.h>
#include <cstdint>
#include <cstddef>

// LSTMCreature, seq_len=1, h0=c0=0:
//   per layer: g = x @ Wih(gate rows).T + (bih+bhh); h = sig(go)*tanh(sig(gi)*tanh(gg))
//   f-gate skipped (multiplies c0=0), W_hh unused (h0=0).
// fp16 hi/lo 3-pass MFMA (Ootomo): x*w ~= xh*wh + xl*wh + xh*wl
//
// R4: counted-vmcnt pipeline (T3+T4): raw s_barrier + s_waitcnt vmcnt(N>0),
// 2-deep global_load_lds prefetch, setprio around MFMA cluster (T5).

#define NROWS 16384
#define HSZ   256

typedef _Float16 half8  __attribute__((ext_vector_type(8)));
typedef _Float16 half4v __attribute__((ext_vector_type(4)));
typedef float    f32x4  __attribute__((ext_vector_type(4)));

#define VMW(n)  asm volatile("s_waitcnt vmcnt(" #n ")" ::: "memory")
#define LGKM0   asm volatile("s_waitcnt lgkmcnt(0)" ::: "memory")
#define SCHED0  __builtin_amdgcn_sched_barrier(0)
#define BAR()   __builtin_amdgcn_s_barrier()

__device__ __forceinline__ void gld16(const void* g, void* l) {
    __builtin_amdgcn_global_load_lds(
        (const __attribute__((address_space(1))) void*)g,
        (__attribute__((address_space(3))) void*)l, 16, 0, 0);
}

__device__ __forceinline__ float fsig(float x)  { return 1.f / (1.f + __expf(-x)); }
__device__ __forceinline__ float ftanh(float x) { float e = __expf(2.f * x); return 1.f - 2.f / (e + 1.f); }

__device__ __forceinline__ int gate_remap(int row) {   // 768-row id -> 1024-row src (gates i,g,o)
    int g8 = row >> 8;
    int gate = (g8 == 0) ? 0 : g8 + 1;
    return gate * 256 + (row & 255);
}

// ---------------- fused prep: x split + W0/1/2 split + bsums ----------------

#define PS0 524288            /* x chunks: 16384*128/4 */
#define PS1 (PS0 + 24576)     /* W0: 768*32 */
#define PS2 (PS1 + 49152)     /* W1: 768*64 */
#define PS3 (PS2 + 49152)     /* W2 */
#define PS4 (PS3 + 2304)      /* bsums */

__global__ __launch_bounds__(256)
void prep_all_kernel(const float* __restrict__ x,
                     const float* __restrict__ W0, const float* __restrict__ b0i, const float* __restrict__ b0h,
                     const float* __restrict__ W1, const float* __restrict__ b1i, const float* __restrict__ b1h,
                     const float* __restrict__ W2, const float* __restrict__ b2i, const float* __restrict__ b2h,
                     _Float16* __restrict__ xh, _Float16* __restrict__ xl,
                     _Float16* __restrict__ W0h, _Float16* __restrict__ W0l,
                     _Float16* __restrict__ W1h, _Float16* __restrict__ W1l,
                     _Float16* __restrict__ W2h, _Float16* __restrict__ W2l,
                     float* __restrict__ bs0, float* __restrict__ bs1, float* __restrict__ bs2)
{
    const int gid = blockIdx.x * 256 + threadIdx.x;
    if (gid < PS0) {
        f32x4 v = ((const f32x4*)x)[gid];
        half4v h, l;
#pragma unroll
        for (int j = 0; j < 4; ++j) { _Float16 hh = (_Float16)v[j]; h[j] = hh; l[j] = (_Float16)(v[j] - (float)hh); }
        ((half4v*)xh)[gid] = h;
        ((half4v*)xl)[gid] = l;
    } else if (gid < PS3) {
        const float* W; _Float16 *Wh, *Wl; int j, K;
        if (gid < PS1)      { j = gid - PS0; K = 128; W = W0; Wh = W0h; Wl = W0l; }
        else if (gid < PS2) { j = gid - PS1; K = 256; W = W1; Wh = W1h; Wl = W1l; }
        else                { j = gid - PS2; K = 256; W = W2; Wh = W2h; Wl = W2l; }
        const int K4 = K >> 2;
        int row = j / K4, k4 = j - row * K4;
        int src = gate_remap(row);
        f32x4 v = *(const f32x4*)(W + (size_t)src * K + k4 * 4);
        half4v h, l;
#pragma unroll
        for (int jj = 0; jj < 4; ++jj) { _Float16 hh = (_Float16)v[jj]; h[jj] = hh; l[jj] = (_Float16)(v[jj] - (float)hh); }
        *(half4v*)(Wh + (size_t)row * K + k4 * 4) = h;
        *(half4v*)(Wl + (size_t)row * K + k4 * 4) = l;
    } else if (gid < PS4) {
        int j = gid - PS3;
        int l = (j >= 1536) ? 2 : (j >= 768 ? 1 : 0);
        int r = j - l * 768;
        int src = gate_remap(r);
        const float* bi = (l == 0) ? b0i : (l == 1) ? b1i : b2i;
        const float* bh = (l == 0) ? b0h : (l == 1) ? b1h : b2h;
        float* bs       = (l == 0) ? bs0 : (l == 1) ? bs1 : bs2;
        bs[r] = bi[src] + bh[src];
    }
}

// ---------------- MFMA layer kernel: counted-vmcnt 2-deep pipeline ----------------
// LDS rows = 128B = 8x16B chunks: c<4 -> hi plane kb=c; c>=4 -> lo plane kb=c-4.
// Physical chunk p holds logical chunk p ^ (row&7) (swizzle on SOURCE; linear dest).
// Per stage: 7 gld16 per thread (4 A + 3 W). vmcnt(7) => previous tile landed.

template<int K>
__global__ __launch_bounds__(256)
void lstm_mfma_kernel(const _Float16* __restrict__ Ah, const _Float16* __restrict__ Al, // [NROWS][K]
                      const _Float16* __restrict__ Wh, const _Float16* __restrict__ Wl, // [768][K]
                      const float* __restrict__ bsum,                                   // [768]
                      _Float16* __restrict__ Oh, _Float16* __restrict__ Ol)             // [NROWS][256]
{
    __shared__ __align__(16) _Float16 sA[2][128 * 64];   // 16KB each
    __shared__ __align__(16) _Float16 sW[2][96 * 64];    // 12KB each

    const int t    = threadIdx.x;
    const int lane = t & 63;
    const int wave = t >> 6;
    const int wm   = wave >> 1;
    const int wn   = wave & 1;
    const int lrow = lane & 15;
    const int lkb  = lane >> 4;
    const int n0   = blockIdx.x * 32;
    const int m0   = blockIdx.y * 128;
    constexpr int NT = K / 32;

    f32x4 acc[3][4];
#pragma unroll
    for (int g = 0; g < 3; ++g)
#pragma unroll
        for (int fm = 0; fm < 4; ++fm) acc[g][fm] = (f32x4)0.f;

    auto stage = [&](int bi, int kt) {
        const int k0 = kt * 32;
#pragma unroll
        for (int i = 0; i < 4; ++i) {
            int idx = i * 256 + t;
            int row = idx >> 3, p = idx & 7;
            int c = p ^ (row & 7);
            const _Float16* base = (c & 4) ? Al : Ah;
            gld16(base + (size_t)(m0 + row) * K + k0 + (c & 3) * 8, &sA[bi][idx * 8]);
        }
#pragma unroll
        for (int i = 0; i < 3; ++i) {
            int idx = i * 256 + t;
            int row = idx >> 3, p = idx & 7;
            int c = p ^ (row & 7);
            int grow = (row >> 5) * 256 + n0 + (row & 31);
            const _Float16* base = (c & 4) ? Wl : Wh;
            gld16(base + (size_t)grow * K + k0 + (c & 3) * 8, &sW[bi][idx * 8]);
        }
    };

    auto compute = [&](int bi) {
        half8 xh[4], xl[4];
#pragma unroll
        for (int fm = 0; fm < 4; ++fm) {
            int r = wm * 64 + fm * 16 + lrow;
            int rb = r * 64;
            xh[fm] = *(const half8*)(&sA[bi][rb + ((lkb       ^ (r & 7)) << 3)]);
            xl[fm] = *(const half8*)(&sA[bi][rb + (((4 | lkb) ^ (r & 7)) << 3)]);
        }
        half8 wwh[3], wwl[3];
#pragma unroll
        for (int g = 0; g < 3; ++g) {
            int r = g * 32 + wn * 16 + lrow;
            int rb = r * 64;
            wwh[g] = *(const half8*)(&sW[bi][rb + ((lkb       ^ (r & 7)) << 3)]);
            wwl[g] = *(const half8*)(&sW[bi][rb + (((4 | lkb) ^ (r & 7)) << 3)]);
        }
        __builtin_amdgcn_s_setprio(1);
#pragma unroll
        for (int g = 0; g < 3; ++g)
#pragma unroll
            for (int fm = 0; fm < 4; ++fm) {
                acc[g][fm] = __builtin_amdgcn_mfma_f32_16x16x32_f16(wwh[g], xh[fm], acc[g][fm], 0, 0, 0);
                acc[g][fm] = __builtin_amdgcn_mfma_f32_16x16x32_f16(wwh[g], xl[fm], acc[g][fm], 0, 0, 0);
                acc[g][fm] = __builtin_amdgcn_mfma_f32_16x16x32_f16(wwl[g], xh[fm], acc[g][fm], 0, 0, 0);
            }
        __builtin_amdgcn_s_setprio(0);
    };

    stage(0, 0);
    stage(1, 1);                       // 14 loads/thread in flight
    for (int kt = 0; kt < NT; ++kt) {
        if (kt < NT - 1) { VMW(7); }   // tile kt landed; tile kt+1 still in flight
        else             { VMW(0); }
        BAR();                         // all waves' tile-kt loads landed
        SCHED0;
        compute(kt & 1);
        LGKM0;                         // own ds_reads fully retired
        BAR();                         // all waves done reading buf kt&1
        SCHED0;
        if (kt + 2 < NT) stage(kt & 1, kt + 2);   // refill freed buffer
    }

    // epilogue: n = n0 + wn*16 + lkb*4 + j ; m = m0 + wm*64 + fm*16 + lrow
    const int nbase = n0 + wn * 16 + lkb * 4;
    const f32x4 bI = *(const f32x4*)(bsum + nbase);
    const f32x4 bG = *(const f32x4*)(bsum + 256 + nbase);
    const f32x4 bO = *(const f32x4*)(bsum + 512 + nbase);

#pragma unroll
    for (int fm = 0; fm < 4; ++fm) {
        const int m = m0 + wm * 64 + fm * 16 + lrow;
        half4v oh, ol;
#pragma unroll
        for (int j = 0; j < 4; ++j) {
            float gi = acc[0][fm][j] + bI[j];
            float gg = acc[1][fm][j] + bG[j];
            float go = acc[2][fm][j] + bO[j];
            float c2 = fsig(gi) * ftanh(gg);
            float h  = fsig(go) * ftanh(c2);
            _Float16 hh = (_Float16)h;
            oh[j] = hh;
            ol[j] = (_Float16)(h - (float)hh);
        }
        *(half4v*)(Oh + (size_t)m * HSZ + nbase) = oh;
        *(half4v*)(Ol + (size_t)m * HSZ + nbase) = ol;
    }
}

// ---------------- FC (MFMA) + fused tanh-softmax-normalize ----------------
// BM=64 rows/block, 256 blocks. fcW converted to hi/lo fp16 in LDS (swizzled).
// H staged with counted-vmcnt pipeline (2 loads/thread per stage).

__global__ __launch_bounds__(256)
void fc_softmax_kernel(const _Float16* __restrict__ hhi, const _Float16* __restrict__ hlo,
                       const float* __restrict__ fcW, const float* __restrict__ fcb,
                       float* __restrict__ out)
{
    __shared__ __align__(16) _Float16 sWh[64 * 256];   // 32KB
    __shared__ __align__(16) _Float16 sWl[64 * 256];   // 32KB
    __shared__ __align__(16) _Float16 sH[2][64 * 64];  // 8KB each

    const int t    = threadIdx.x;
    const int lane = t & 63;
    const int wave = t >> 6;
    const int ln   = lane & 15;
    const int lkb  = lane >> 4;
    const int m0   = blockIdx.x * 64;

    auto stageH = [&](int bi, int kt) {
#pragma unroll
        for (int i = 0; i < 2; ++i) {
            int idx = i * 256 + t;
            int row = idx >> 3, p = idx & 7;
            int c = p ^ (row & 7);
            const _Float16* base = (c & 4) ? hlo : hhi;
            gld16(base + (size_t)(m0 + row) * 256 + kt * 32 + (c & 3) * 8, &sH[bi][idx * 8]);
        }
    };

    stageH(0, 0);
    stageH(1, 1);

    // convert fcW (64x256 f32) -> hi/lo fp16 LDS, 16B-chunk XOR swizzle
#pragma unroll
    for (int i = 0; i < 8; ++i) {
        int idx = i * 256 + t;            // 0..2047
        int row = idx >> 5, c = idx & 31; // chunk = 8 k
        const float* src = fcW + (size_t)row * 256 + c * 8;
        f32x4 v0 = *(const f32x4*)src;
        f32x4 v1 = *(const f32x4*)(src + 4);
        half8 h, l;
#pragma unroll
        for (int j = 0; j < 4; ++j) {
            _Float16 h0 = (_Float16)v0[j]; h[j]     = h0; l[j]     = (_Float16)(v0[j] - (float)h0);
            _Float16 h1 = (_Float16)v1[j]; h[4 + j] = h1; l[4 + j] = (_Float16)(v1[j] - (float)h1);
        }
        int off = row * 256 + ((c ^ (row & 7)) << 3);
        *(half8*)(sWh + off) = h;
        *(half8*)(sWl + off) = l;
    }

    f32x4 acc[4];
#pragma unroll
    for (int nf = 0; nf < 4; ++nf) acc[nf] = (f32x4)0.f;

    auto computeF = [&](int bi, int kt) {
        const int r  = wave * 16 + ln;
        const int rb = r * 64;
        half8 ah = *(const half8*)(&sH[bi][rb + ((lkb       ^ (r & 7)) << 3)]);
        half8 al = *(const half8*)(&sH[bi][rb + (((4 | lkb) ^ (r & 7)) << 3)]);
        __builtin_amdgcn_s_setprio(1);
#pragma unroll
        for (int nf = 0; nf < 4; ++nf) {
            int wr  = nf * 16 + ln;
            int ch  = kt * 4 + lkb;                 // logical 16B chunk in row (0..31)
            int off = wr * 256 + ((ch ^ (wr & 7)) << 3);
            half8 wwh = *(const half8*)(&sWh[off]);
            half8 wwl = *(const half8*)(&sWl[off]);
            acc[nf] = __builtin_amdgcn_mfma_f32_16x16x32_f16(ah, wwh, acc[nf], 0, 0, 0);
            acc[nf] = __builtin_amdgcn_mfma_f32_16x16x32_f16(al, wwh, acc[nf], 0, 0, 0);
            acc[nf] = __builtin_amdgcn_mfma_f32_16x16x32_f16(ah, wwl, acc[nf], 0, 0, 0);
        }
        __builtin_amdgcn_s_setprio(0);
    };

    __syncthreads();   // one-time: drains fcW ds_writes + prologue stages (vmcnt 0)

    for (int kt = 0; kt < 8; ++kt) {
        if (kt >= 2) {                    // tiles 0,1 covered by syncthreads
            if (kt < 7) { VMW(2); }       // tile kt landed; kt+1 in flight
            else        { VMW(0); }
        }
        BAR();
        SCHED0;
        computeF(kt & 1, kt);
        LGKM0;
        BAR();
        SCHED0;
        if (kt + 2 < 8) stageH(kt & 1, kt + 2);
    }

    // ---- epilogue: bias + tanh-softmax-normalize over n (64) per row ----
    float fb[4];
#pragma unroll
    for (int nf = 0; nf < 4; ++nf) fb[nf] = fcb[nf * 16 + ln];

    float tt[4][4], aa[4][4];
#pragma unroll
    for (int nf = 0; nf < 4; ++nf)
#pragma unroll
        for (int r = 0; r < 4; ++r) {
            float o = acc[nf][r] + fb[nf];
            tt[nf][r] = ftanh(o);
            aa[nf][r] = fabsf(o);
        }

    float mx[4];
#pragma unroll
    for (int r = 0; r < 4; ++r)
        mx[r] = fmaxf(fmaxf(aa[0][r], aa[1][r]), fmaxf(aa[2][r], aa[3][r]));
#pragma unroll
    for (int ofs = 1; ofs < 16; ofs <<= 1)
#pragma unroll
        for (int r = 0; r < 4; ++r) mx[r] = fmaxf(mx[r], __shfl_xor(mx[r], ofs, 64));

    float ee[4][4], Z[4];
#pragma unroll
    for (int r = 0; r < 4; ++r) Z[r] = 0.f;
#pragma unroll
    for (int nf = 0; nf < 4; ++nf)
#pragma unroll
        for (int r = 0; r < 4; ++r) { ee[nf][r] = __expf(aa[nf][r] - mx[r]); Z[r] += ee[nf][r]; }
#pragma unroll
    for (int ofs = 1; ofs < 16; ofs <<= 1)
#pragma unroll
        for (int r = 0; r < 4; ++r) Z[r] += __shfl_xor(Z[r], ofs, 64);

    float w[4][4], S[4];
#pragma unroll
    for (int r = 0; r < 4; ++r) S[r] = 0.f;
#pragma unroll
    for (int nf = 0; nf < 4; ++nf)
#pragma unroll
        for (int r = 0; r < 4; ++r) { w[nf][r] = tt[nf][r] * ee[nf][r] / Z[r]; S[r] += fabsf(w[nf][r]); }
#pragma unroll
    for (int ofs = 1; ofs < 16; ofs <<= 1)
#pragma unroll
        for (int r = 0; r < 4; ++r) S[r] += __shfl_xor(S[r], ofs, 64);

#pragma unroll
    for (int r = 0; r < 4; ++r) {
        const float inv = 1.f / fmaxf(S[r], 1e-12f);
        const int m = m0 + wave * 16 + lkb * 4 + r;
#pragma unroll
        for (int nf = 0; nf < 4; ++nf)
            out[(size_t)m * 64 + nf * 16 + ln] = w[nf][r] * inv;
    }
}

// ---------------- launch ----------------

extern "C" void kernel_launch(void* const* d_in, const int* in_sizes, int n_in,
                              void* d_out, int out_size, void* d_ws, size_t ws_size,
                              hipStream_t stream) {
    const float* x    = (const float*)d_in[0];
    const float* Wih0 = (const float*)d_in[1];
    const float* bih0 = (const float*)d_in[3];
    const float* bhh0 = (const float*)d_in[4];
    const float* Wih1 = (const float*)d_in[5];
    const float* bih1 = (const float*)d_in[7];
    const float* bhh1 = (const float*)d_in[8];
    const float* Wih2 = (const float*)d_in[9];
    const float* bih2 = (const float*)d_in[11];
    const float* bhh2 = (const float*)d_in[12];
    const float* fcW  = (const float*)d_in[13];
    const float* fcb  = (const float*)d_in[14];

    char* ws = (char*)d_ws;
    _Float16* hA_hi = (_Float16*)(ws);                 // 8 MB
    _Float16* hA_lo = (_Float16*)(ws + (8u  << 20));   // 8 MB
    _Float16* hB_hi = (_Float16*)(ws + (16u << 20));   // 8 MB
    _Float16* hB_lo = (_Float16*)(ws + (24u << 20));   // 8 MB
    _Float16* xh    = hB_hi;                           // 4 MB (dead after layer 1)
    _Float16* xl    = (_Float16*)(ws + (20u << 20));   // 4 MB

    // W planes + bsums live in d_out (4 MB), fully consumed before fc writes out.
    char* ob = (char*)d_out;
    _Float16* W0h = (_Float16*)(ob);
    _Float16* W0l = (_Float16*)(ob + 196608);
    _Float16* W1h = (_Float16*)(ob + 393216);
    _Float16* W1l = (_Float16*)(ob + 786432);
    _Float16* W2h = (_Float16*)(ob + 1179648);
    _Float16* W2l = (_Float16*)(ob + 1572864);
    float*    bs0 = (float*)(ob + 1966080);
    float*    bs1 = (float*)(ob + 1969152);
    float*    bs2 = (float*)(ob + 1972224);
    float*    outp = (float*)d_out;

    dim3 blk(256);
    dim3 lgrid(8, 128);

    prep_all_kernel<<<dim3(PS4 / 256), blk, 0, stream>>>(
        x, Wih0, bih0, bhh0, Wih1, bih1, bhh1, Wih2, bih2, bhh2,
        xh, xl, W0h, W0l, W1h, W1l, W2h, W2l, bs0, bs1, bs2);

    lstm_mfma_kernel<128><<<lgrid, blk, 0, stream>>>(xh, xl, W0h, W0l, bs0, hA_hi, hA_lo);
    lstm_mfma_kernel<256><<<lgrid, blk, 0, stream>>>(hA_hi, hA_lo, W1h, W1l, bs1, hB_hi, hB_lo);
    lstm_mfma_kernel<256><<<lgrid, blk, 0, stream>>>(hB_hi, hB_lo, W2h, W2l, bs2, hA_hi, hA_lo);

    fc_softmax_kernel<<<dim3(NROWS / 64), blk, 0, stream>>>(hA_hi, hA_lo, fcW, fcb, outp);
}

// Round 5
// 101.001 us; speedup vs baseline: 1.1339x; 1.1339x over previous
//
#include <hip/hip_runtime.h>
#include <cstdint>
#include <cstddef>

// LSTMCreature, seq_len=1, h0=c0=0:
//   per layer: g = x @ Wih(gate rows).T + (bih+bhh); h = sig(go)*tanh(sig(gi)*tanh(gg))
//   f-gate skipped (multiplies c0=0), W_hh unused (h0=0).
// fp16 hi/lo 3-pass MFMA (Ootomo): x*w ~= xh*wh + xl*wh + xh*wl
//
// R5: XCD-locality block swizzle. All 8 n-blocks of an m-block map to the SAME
// XCD (bid%8 == M%8), so the A-planes are fetched from HBM once per XCD and
// re-read from L2; layer L's h-writes are consumed by layer L+1 on the same
// XCD (write-back L2 hit). Counted-vmcnt pipeline (T3+T4) + setprio (T5) kept.

#define NROWS 16384
#define HSZ   256

typedef _Float16 half8  __attribute__((ext_vector_type(8)));
typedef _Float16 half4v __attribute__((ext_vector_type(4)));
typedef float    f32x4  __attribute__((ext_vector_type(4)));

#define VMW(n)  asm volatile("s_waitcnt vmcnt(" #n ")" ::: "memory")
#define LGKM0   asm volatile("s_waitcnt lgkmcnt(0)" ::: "memory")
#define SCHED0  __builtin_amdgcn_sched_barrier(0)
#define BAR()   __builtin_amdgcn_s_barrier()

__device__ __forceinline__ void gld16(const void* g, void* l) {
    __builtin_amdgcn_global_load_lds(
        (const __attribute__((address_space(1))) void*)g,
        (__attribute__((address_space(3))) void*)l, 16, 0, 0);
}

__device__ __forceinline__ float fsig(float x)  { return 1.f / (1.f + __expf(-x)); }
__device__ __forceinline__ float ftanh(float x) { float e = __expf(2.f * x); return 1.f - 2.f / (e + 1.f); }

__device__ __forceinline__ int gate_remap(int row) {   // 768-row id -> 1024-row src (gates i,g,o)
    int g8 = row >> 8;
    int gate = (g8 == 0) ? 0 : g8 + 1;
    return gate * 256 + (row & 255);
}

// ---------------- fused prep: x split + W0/1/2 split + bsums ----------------

#define PS0 524288            /* x chunks: 16384*128/4 */
#define PS1 (PS0 + 24576)     /* W0: 768*32 */
#define PS2 (PS1 + 49152)     /* W1: 768*64 */
#define PS3 (PS2 + 49152)     /* W2 */
#define PS4 (PS3 + 2304)      /* bsums */

__global__ __launch_bounds__(256)
void prep_all_kernel(const float* __restrict__ x,
                     const float* __restrict__ W0, const float* __restrict__ b0i, const float* __restrict__ b0h,
                     const float* __restrict__ W1, const float* __restrict__ b1i, const float* __restrict__ b1h,
                     const float* __restrict__ W2, const float* __restrict__ b2i, const float* __restrict__ b2h,
                     _Float16* __restrict__ xh, _Float16* __restrict__ xl,
                     _Float16* __restrict__ W0h, _Float16* __restrict__ W0l,
                     _Float16* __restrict__ W1h, _Float16* __restrict__ W1l,
                     _Float16* __restrict__ W2h, _Float16* __restrict__ W2l,
                     float* __restrict__ bs0, float* __restrict__ bs1, float* __restrict__ bs2)
{
    const int gid = blockIdx.x * 256 + threadIdx.x;
    if (gid < PS0) {
        f32x4 v = ((const f32x4*)x)[gid];
        half4v h, l;
#pragma unroll
        for (int j = 0; j < 4; ++j) { _Float16 hh = (_Float16)v[j]; h[j] = hh; l[j] = (_Float16)(v[j] - (float)hh); }
        ((half4v*)xh)[gid] = h;
        ((half4v*)xl)[gid] = l;
    } else if (gid < PS3) {
        const float* W; _Float16 *Wh, *Wl; int j, K;
        if (gid < PS1)      { j = gid - PS0; K = 128; W = W0; Wh = W0h; Wl = W0l; }
        else if (gid < PS2) { j = gid - PS1; K = 256; W = W1; Wh = W1h; Wl = W1l; }
        else                { j = gid - PS2; K = 256; W = W2; Wh = W2h; Wl = W2l; }
        const int K4 = K >> 2;
        int row = j / K4, k4 = j - row * K4;
        int src = gate_remap(row);
        f32x4 v = *(const f32x4*)(W + (size_t)src * K + k4 * 4);
        half4v h, l;
#pragma unroll
        for (int jj = 0; jj < 4; ++jj) { _Float16 hh = (_Float16)v[jj]; h[jj] = hh; l[jj] = (_Float16)(v[jj] - (float)hh); }
        *(half4v*)(Wh + (size_t)row * K + k4 * 4) = h;
        *(half4v*)(Wl + (size_t)row * K + k4 * 4) = l;
    } else if (gid < PS4) {
        int j = gid - PS3;
        int l = (j >= 1536) ? 2 : (j >= 768 ? 1 : 0);
        int r = j - l * 768;
        int src = gate_remap(r);
        const float* bi = (l == 0) ? b0i : (l == 1) ? b1i : b2i;
        const float* bh = (l == 0) ? b0h : (l == 1) ? b1h : b2h;
        float* bs       = (l == 0) ? bs0 : (l == 1) ? bs1 : bs2;
        bs[r] = bi[src] + bh[src];
    }
}

// ---------------- MFMA layer kernel: counted-vmcnt + XCD-local swizzle ----------------
// 1D grid 1024. bid -> (c=bid&7, q=bid>>3): n0=(q&7)*32, M=c+8*(q>>3), m0=M*128.
// All 8 n-blocks of m-block M have bid % 8 == M % 8 -> same XCD L2 (A fetched once).
// LDS rows = 128B = 8x16B chunks: c<4 -> hi plane kb=c; c>=4 -> lo plane kb=c-4.
// Physical chunk p holds logical chunk p ^ (row&7) (swizzle on SOURCE; linear dest).

template<int K>
__global__ __launch_bounds__(256)
void lstm_mfma_kernel(const _Float16* __restrict__ Ah, const _Float16* __restrict__ Al, // [NROWS][K]
                      const _Float16* __restrict__ Wh, const _Float16* __restrict__ Wl, // [768][K]
                      const float* __restrict__ bsum,                                   // [768]
                      _Float16* __restrict__ Oh, _Float16* __restrict__ Ol)             // [NROWS][256]
{
    __shared__ __align__(16) _Float16 sA[2][128 * 64];   // 16KB each
    __shared__ __align__(16) _Float16 sW[2][96 * 64];    // 12KB each

    const int t    = threadIdx.x;
    const int lane = t & 63;
    const int wave = t >> 6;
    const int wm   = wave >> 1;
    const int wn   = wave & 1;
    const int lrow = lane & 15;
    const int lkb  = lane >> 4;

    const int bid = blockIdx.x;
    const int xc  = bid & 7, q = bid >> 3;
    const int n0  = (q & 7) * 32;
    const int m0  = (xc + ((q >> 3) << 3)) * 128;
    constexpr int NT = K / 32;

    f32x4 acc[3][4];
#pragma unroll
    for (int g = 0; g < 3; ++g)
#pragma unroll
        for (int fm = 0; fm < 4; ++fm) acc[g][fm] = (f32x4)0.f;

    auto stage = [&](int bi, int kt) {
        const int k0 = kt * 32;
#pragma unroll
        for (int i = 0; i < 4; ++i) {
            int idx = i * 256 + t;
            int row = idx >> 3, p = idx & 7;
            int c = p ^ (row & 7);
            const _Float16* base = (c & 4) ? Al : Ah;
            gld16(base + (size_t)(m0 + row) * K + k0 + (c & 3) * 8, &sA[bi][idx * 8]);
        }
#pragma unroll
        for (int i = 0; i < 3; ++i) {
            int idx = i * 256 + t;
            int row = idx >> 3, p = idx & 7;
            int c = p ^ (row & 7);
            int grow = (row >> 5) * 256 + n0 + (row & 31);
            const _Float16* base = (c & 4) ? Wl : Wh;
            gld16(base + (size_t)grow * K + k0 + (c & 3) * 8, &sW[bi][idx * 8]);
        }
    };

    auto compute = [&](int bi) {
        half8 xh[4], xl[4];
#pragma unroll
        for (int fm = 0; fm < 4; ++fm) {
            int r = wm * 64 + fm * 16 + lrow;
            int rb = r * 64;
            xh[fm] = *(const half8*)(&sA[bi][rb + ((lkb       ^ (r & 7)) << 3)]);
            xl[fm] = *(const half8*)(&sA[bi][rb + (((4 | lkb) ^ (r & 7)) << 3)]);
        }
        half8 wwh[3], wwl[3];
#pragma unroll
        for (int g = 0; g < 3; ++g) {
            int r = g * 32 + wn * 16 + lrow;
            int rb = r * 64;
            wwh[g] = *(const half8*)(&sW[bi][rb + ((lkb       ^ (r & 7)) << 3)]);
            wwl[g] = *(const half8*)(&sW[bi][rb + (((4 | lkb) ^ (r & 7)) << 3)]);
        }
        __builtin_amdgcn_s_setprio(1);
#pragma unroll
        for (int g = 0; g < 3; ++g)
#pragma unroll
            for (int fm = 0; fm < 4; ++fm) {
                acc[g][fm] = __builtin_amdgcn_mfma_f32_16x16x32_f16(wwh[g], xh[fm], acc[g][fm], 0, 0, 0);
                acc[g][fm] = __builtin_amdgcn_mfma_f32_16x16x32_f16(wwh[g], xl[fm], acc[g][fm], 0, 0, 0);
                acc[g][fm] = __builtin_amdgcn_mfma_f32_16x16x32_f16(wwl[g], xh[fm], acc[g][fm], 0, 0, 0);
            }
        __builtin_amdgcn_s_setprio(0);
    };

    stage(0, 0);
    stage(1, 1);                       // 14 loads/thread in flight
    for (int kt = 0; kt < NT; ++kt) {
        if (kt < NT - 1) { VMW(7); }   // tile kt landed; tile kt+1 still in flight
        else             { VMW(0); }
        BAR();                         // all waves' tile-kt loads landed
        SCHED0;
        compute(kt & 1);
        LGKM0;                         // own ds_reads fully retired
        BAR();                         // all waves done reading buf kt&1
        SCHED0;
        if (kt + 2 < NT) stage(kt & 1, kt + 2);   // refill freed buffer
    }

    // epilogue: n = n0 + wn*16 + lkb*4 + j ; m = m0 + wm*64 + fm*16 + lrow
    const int nbase = n0 + wn * 16 + lkb * 4;
    const f32x4 bI = *(const f32x4*)(bsum + nbase);
    const f32x4 bG = *(const f32x4*)(bsum + 256 + nbase);
    const f32x4 bO = *(const f32x4*)(bsum + 512 + nbase);

#pragma unroll
    for (int fm = 0; fm < 4; ++fm) {
        const int m = m0 + wm * 64 + fm * 16 + lrow;
        half4v oh, ol;
#pragma unroll
        for (int j = 0; j < 4; ++j) {
            float gi = acc[0][fm][j] + bI[j];
            float gg = acc[1][fm][j] + bG[j];
            float go = acc[2][fm][j] + bO[j];
            float c2 = fsig(gi) * ftanh(gg);
            float h  = fsig(go) * ftanh(c2);
            _Float16 hh = (_Float16)h;
            oh[j] = hh;
            ol[j] = (_Float16)(h - (float)hh);
        }
        *(half4v*)(Oh + (size_t)m * HSZ + nbase) = oh;
        *(half4v*)(Ol + (size_t)m * HSZ + nbase) = ol;
    }
}

// ---------------- FC (MFMA) + fused tanh-softmax-normalize ----------------
// BM=64 rows/block, 256 blocks, XCD-swizzled so fc block reading layer-3
// m-block M lands on XCD M%8 (h rows still in that XCD's L2).

__global__ __launch_bounds__(256)
void fc_softmax_kernel(const _Float16* __restrict__ hhi, const _Float16* __restrict__ hlo,
                       const float* __restrict__ fcW, const float* __restrict__ fcb,
                       float* __restrict__ out)
{
    __shared__ __align__(16) _Float16 sWh[64 * 256];   // 32KB
    __shared__ __align__(16) _Float16 sWl[64 * 256];   // 32KB
    __shared__ __align__(16) _Float16 sH[2][64 * 64];  // 8KB each

    const int t    = threadIdx.x;
    const int lane = t & 63;
    const int wave = t >> 6;
    const int ln   = lane & 15;
    const int lkb  = lane >> 4;

    const int bid = blockIdx.x;
    // f = 2*(bid&7) + bit3(bid) + 16*(bid>>4): f/2 == bid (mod 8) -> same XCD as writer
    const int f   = (((bid & 7) << 1) | ((bid >> 3) & 1)) | ((bid >> 4) << 4);
    const int m0  = f * 64;

    auto stageH = [&](int bi, int kt) {
#pragma unroll
        for (int i = 0; i < 2; ++i) {
            int idx = i * 256 + t;
            int row = idx >> 3, p = idx & 7;
            int c = p ^ (row & 7);
            const _Float16* base = (c & 4) ? hlo : hhi;
            gld16(base + (size_t)(m0 + row) * 256 + kt * 32 + (c & 3) * 8, &sH[bi][idx * 8]);
        }
    };

    stageH(0, 0);
    stageH(1, 1);

    // convert fcW (64x256 f32) -> hi/lo fp16 LDS, 16B-chunk XOR swizzle
#pragma unroll
    for (int i = 0; i < 8; ++i) {
        int idx = i * 256 + t;            // 0..2047
        int row = idx >> 5, c = idx & 31; // chunk = 8 k
        const float* src = fcW + (size_t)row * 256 + c * 8;
        f32x4 v0 = *(const f32x4*)src;
        f32x4 v1 = *(const f32x4*)(src + 4);
        half8 h, l;
#pragma unroll
        for (int j = 0; j < 4; ++j) {
            _Float16 h0 = (_Float16)v0[j]; h[j]     = h0; l[j]     = (_Float16)(v0[j] - (float)h0);
            _Float16 h1 = (_Float16)v1[j]; h[4 + j] = h1; l[4 + j] = (_Float16)(v1[j] - (float)h1);
        }
        int off = row * 256 + ((c ^ (row & 7)) << 3);
        *(half8*)(sWh + off) = h;
        *(half8*)(sWl + off) = l;
    }

    f32x4 acc[4];
#pragma unroll
    for (int nf = 0; nf < 4; ++nf) acc[nf] = (f32x4)0.f;

    auto computeF = [&](int bi, int kt) {
        const int r  = wave * 16 + ln;
        const int rb = r * 64;
        half8 ah = *(const half8*)(&sH[bi][rb + ((lkb       ^ (r & 7)) << 3)]);
        half8 al = *(const half8*)(&sH[bi][rb + (((4 | lkb) ^ (r & 7)) << 3)]);
        __builtin_amdgcn_s_setprio(1);
#pragma unroll
        for (int nf = 0; nf < 4; ++nf) {
            int wr  = nf * 16 + ln;
            int ch  = kt * 4 + lkb;                 // logical 16B chunk in row (0..31)
            int off = wr * 256 + ((ch ^ (wr & 7)) << 3);
            half8 wwh = *(const half8*)(&sWh[off]);
            half8 wwl = *(const half8*)(&sWl[off]);
            acc[nf] = __builtin_amdgcn_mfma_f32_16x16x32_f16(ah, wwh, acc[nf], 0, 0, 0);
            acc[nf] = __builtin_amdgcn_mfma_f32_16x16x32_f16(al, wwh, acc[nf], 0, 0, 0);
            acc[nf] = __builtin_amdgcn_mfma_f32_16x16x32_f16(ah, wwl, acc[nf], 0, 0, 0);
        }
        __builtin_amdgcn_s_setprio(0);
    };

    __syncthreads();   // one-time: drains fcW ds_writes + prologue stages (vmcnt 0)

    for (int kt = 0; kt < 8; ++kt) {
        if (kt >= 2) {                    // tiles 0,1 covered by syncthreads
            if (kt < 7) { VMW(2); }       // tile kt landed; kt+1 in flight
            else        { VMW(0); }
        }
        BAR();
        SCHED0;
        computeF(kt & 1, kt);
        LGKM0;
        BAR();
        SCHED0;
        if (kt + 2 < 8) stageH(kt & 1, kt + 2);
    }

    // ---- epilogue: bias + tanh-softmax-normalize over n (64) per row ----
    float fb[4];
#pragma unroll
    for (int nf = 0; nf < 4; ++nf) fb[nf] = fcb[nf * 16 + ln];

    float tt[4][4], aa[4][4];
#pragma unroll
    for (int nf = 0; nf < 4; ++nf)
#pragma unroll
        for (int r = 0; r < 4; ++r) {
            float o = acc[nf][r] + fb[nf];
            tt[nf][r] = ftanh(o);
            aa[nf][r] = fabsf(o);
        }

    float mx[4];
#pragma unroll
    for (int r = 0; r < 4; ++r)
        mx[r] = fmaxf(fmaxf(aa[0][r], aa[1][r]), fmaxf(aa[2][r], aa[3][r]));
#pragma unroll
    for (int ofs = 1; ofs < 16; ofs <<= 1)
#pragma unroll
        for (int r = 0; r < 4; ++r) mx[r] = fmaxf(mx[r], __shfl_xor(mx[r], ofs, 64));

    float ee[4][4], Z[4];
#pragma unroll
    for (int r = 0; r < 4; ++r) Z[r] = 0.f;
#pragma unroll
    for (int nf = 0; nf < 4; ++nf)
#pragma unroll
        for (int r = 0; r < 4; ++r) { ee[nf][r] = __expf(aa[nf][r] - mx[r]); Z[r] += ee[nf][r]; }
#pragma unroll
    for (int ofs = 1; ofs < 16; ofs <<= 1)
#pragma unroll
        for (int r = 0; r < 4; ++r) Z[r] += __shfl_xor(Z[r], ofs, 64);

    float w[4][4], S[4];
#pragma unroll
    for (int r = 0; r < 4; ++r) S[r] = 0.f;
#pragma unroll
    for (int nf = 0; nf < 4; ++nf)
#pragma unroll
        for (int r = 0; r < 4; ++r) { w[nf][r] = tt[nf][r] * ee[nf][r] / Z[r]; S[r] += fabsf(w[nf][r]); }
#pragma unroll
    for (int ofs = 1; ofs < 16; ofs <<= 1)
#pragma unroll
        for (int r = 0; r < 4; ++r) S[r] += __shfl_xor(S[r], ofs, 64);

#pragma unroll
    for (int r = 0; r < 4; ++r) {
        const float inv = 1.f / fmaxf(S[r], 1e-12f);
        const int m = m0 + wave * 16 + lkb * 4 + r;
#pragma unroll
        for (int nf = 0; nf < 4; ++nf)
            out[(size_t)m * 64 + nf * 16 + ln] = w[nf][r] * inv;
    }
}

// ---------------- launch ----------------

extern "C" void kernel_launch(void* const* d_in, const int* in_sizes, int n_in,
                              void* d_out, int out_size, void* d_ws, size_t ws_size,
                              hipStream_t stream) {
    const float* x    = (const float*)d_in[0];
    const float* Wih0 = (const float*)d_in[1];
    const float* bih0 = (const float*)d_in[3];
    const float* bhh0 = (const float*)d_in[4];
    const float* Wih1 = (const float*)d_in[5];
    const float* bih1 = (const float*)d_in[7];
    const float* bhh1 = (const float*)d_in[8];
    const float* Wih2 = (const float*)d_in[9];
    const float* bih2 = (const float*)d_in[11];
    const float* bhh2 = (const float*)d_in[12];
    const float* fcW  = (const float*)d_in[13];
    const float* fcb  = (const float*)d_in[14];

    char* ws = (char*)d_ws;
    _Float16* hA_hi = (_Float16*)(ws);                 // 8 MB
    _Float16* hA_lo = (_Float16*)(ws + (8u  << 20));   // 8 MB
    _Float16* hB_hi = (_Float16*)(ws + (16u << 20));   // 8 MB
    _Float16* hB_lo = (_Float16*)(ws + (24u << 20));   // 8 MB
    _Float16* xh    = hB_hi;                           // 4 MB (dead after layer 1)
    _Float16* xl    = (_Float16*)(ws + (20u << 20));   // 4 MB

    // W planes + bsums live in d_out (4 MB), fully consumed before fc writes out.
    char* ob = (char*)d_out;
    _Float16* W0h = (_Float16*)(ob);
    _Float16* W0l = (_Float16*)(ob + 196608);
    _Float16* W1h = (_Float16*)(ob + 393216);
    _Float16* W1l = (_Float16*)(ob + 786432);
    _Float16* W2h = (_Float16*)(ob + 1179648);
    _Float16* W2l = (_Float16*)(ob + 1572864);
    float*    bs0 = (float*)(ob + 1966080);
    float*    bs1 = (float*)(ob + 1969152);
    float*    bs2 = (float*)(ob + 1972224);
    float*    outp = (float*)d_out;

    dim3 blk(256);

    prep_all_kernel<<<dim3(PS4 / 256), blk, 0, stream>>>(
        x, Wih0, bih0, bhh0, Wih1, bih1, bhh1, Wih2, bih2, bhh2,
        xh, xl, W0h, W0l, W1h, W1l, W2h, W2l, bs0, bs1, bs2);

    lstm_mfma_kernel<128><<<dim3(1024), blk, 0, stream>>>(xh, xl, W0h, W0l, bs0, hA_hi, hA_lo);
    lstm_mfma_kernel<256><<<dim3(1024), blk, 0, stream>>>(hA_hi, hA_lo, W1h, W1l, bs1, hB_hi, hB_lo);
    lstm_mfma_kernel<256><<<dim3(1024), blk, 0, stream>>>(hB_hi, hB_lo, W2h, W2l, bs2, hA_hi, hA_lo);

    fc_softmax_kernel<<<dim3(256), blk, 0, stream>>>(hA_hi, hA_lo, fcW, fcb, outp);
}

// Round 6
// 76.847 us; speedup vs baseline: 1.4904x; 1.3143x over previous
//
#include <hip/hip_runtime.h>
#include <cstdint>
#include <cstddef>

// LSTMCreature, seq_len=1, h0=c0=0:
//   per layer: g = x @ Wih(gate rows).T + (bih+bhh); h = sig(go)*tanh(sig(gi)*tanh(gg))
//   f-gate skipped (multiplies c0=0), W_hh unused (h0=0).
// R6: 2-pass hi/lo on W only:  x*w ~= xh*wh + xh*wl  (= xh*(wh+wl); dropped
// term xl*w ~ 2^-11 * x * w -> ~1.6e-4 gate err, inside threshold).
//   - x / h stored as SINGLE fp16 plane (no lo plane anywhere)
//   - A LDS tile 8KB (row-parity-paired 128B lines, XOR-8 chunk swizzle)
//   - LDS/block 40KB -> 4 blocks/CU (4 waves/SIMD), launch_bounds(256,4)
//   - 24 MFMAs/tile (2 passes), counted vmcnt(5) pipeline, XCD-local swizzle

#define NROWS 16384
#define HSZ   256

typedef _Float16 half8  __attribute__((ext_vector_type(8)));
typedef _Float16 half4v __attribute__((ext_vector_type(4)));
typedef float    f32x4  __attribute__((ext_vector_type(4)));

#define VMW(n)  asm volatile("s_waitcnt vmcnt(" #n ")" ::: "memory")
#define LGKM0   asm volatile("s_waitcnt lgkmcnt(0)" ::: "memory")
#define SCHED0  __builtin_amdgcn_sched_barrier(0)
#define BAR()   __builtin_amdgcn_s_barrier()

__device__ __forceinline__ void gld16(const void* g, void* l) {
    __builtin_amdgcn_global_load_lds(
        (const __attribute__((address_space(1))) void*)g,
        (__attribute__((address_space(3))) void*)l, 16, 0, 0);
}

__device__ __forceinline__ float fsig(float x)  { return 1.f / (1.f + __expf(-x)); }
__device__ __forceinline__ float ftanh(float x) { float e = __expf(2.f * x); return 1.f - 2.f / (e + 1.f); }

__device__ __forceinline__ int gate_remap(int row) {   // 768-row id -> 1024-row src (gates i,g,o)
    int g8 = row >> 8;
    int gate = (g8 == 0) ? 0 : g8 + 1;
    return gate * 256 + (row & 255);
}

// ---------------- fused prep: x -> fp16 hi plane; W0/1/2 -> hi/lo; bsums ----------------

#define PS0 524288            /* x chunks: 16384*128/4 */
#define PS1 (PS0 + 24576)     /* W0: 768*32 */
#define PS2 (PS1 + 49152)     /* W1: 768*64 */
#define PS3 (PS2 + 49152)     /* W2 */
#define PS4 (PS3 + 2304)      /* bsums */

__global__ __launch_bounds__(256)
void prep_all_kernel(const float* __restrict__ x,
                     const float* __restrict__ W0, const float* __restrict__ b0i, const float* __restrict__ b0h,
                     const float* __restrict__ W1, const float* __restrict__ b1i, const float* __restrict__ b1h,
                     const float* __restrict__ W2, const float* __restrict__ b2i, const float* __restrict__ b2h,
                     _Float16* __restrict__ xh,
                     _Float16* __restrict__ W0h, _Float16* __restrict__ W0l,
                     _Float16* __restrict__ W1h, _Float16* __restrict__ W1l,
                     _Float16* __restrict__ W2h, _Float16* __restrict__ W2l,
                     float* __restrict__ bs0, float* __restrict__ bs1, float* __restrict__ bs2)
{
    const int gid = blockIdx.x * 256 + threadIdx.x;
    if (gid < PS0) {
        f32x4 v = ((const f32x4*)x)[gid];
        half4v h;
#pragma unroll
        for (int j = 0; j < 4; ++j) h[j] = (_Float16)v[j];
        ((half4v*)xh)[gid] = h;
    } else if (gid < PS3) {
        const float* W; _Float16 *Wh, *Wl; int j, K;
        if (gid < PS1)      { j = gid - PS0; K = 128; W = W0; Wh = W0h; Wl = W0l; }
        else if (gid < PS2) { j = gid - PS1; K = 256; W = W1; Wh = W1h; Wl = W1l; }
        else                { j = gid - PS2; K = 256; W = W2; Wh = W2h; Wl = W2l; }
        const int K4 = K >> 2;
        int row = j / K4, k4 = j - row * K4;
        int src = gate_remap(row);
        f32x4 v = *(const f32x4*)(W + (size_t)src * K + k4 * 4);
        half4v h, l;
#pragma unroll
        for (int jj = 0; jj < 4; ++jj) { _Float16 hh = (_Float16)v[jj]; h[jj] = hh; l[jj] = (_Float16)(v[jj] - (float)hh); }
        *(half4v*)(Wh + (size_t)row * K + k4 * 4) = h;
        *(half4v*)(Wl + (size_t)row * K + k4 * 4) = l;
    } else if (gid < PS4) {
        int j = gid - PS3;
        int l = (j >= 1536) ? 2 : (j >= 768 ? 1 : 0);
        int r = j - l * 768;
        int src = gate_remap(r);
        const float* bi = (l == 0) ? b0i : (l == 1) ? b1i : b2i;
        const float* bh = (l == 0) ? b0h : (l == 1) ? b1h : b2h;
        float* bs       = (l == 0) ? bs0 : (l == 1) ? bs1 : bs2;
        bs[r] = bi[src] + bh[src];
    }
}

// ---------------- MFMA layer kernel ----------------
// A LDS: 128 rows x 32k single plane as 64 lines of 128B; line L holds rows
// (2L, 2L+1); logical chunk c = ((row&1)<<2)|kc, physical p = c ^ (L&7).
// W LDS: 96 lines of 128B; chunk c = (plane<<2)|kc, p = c ^ (line&7).
// Stage = 2 A + 3 W gld16 per thread -> counted vmcnt(5). XCD swizzle:
// bid -> xc=bid&7, q=bid>>3: n0=(q&7)*32, M=xc+8*(q>>3)  (bid%8 == M%8).

template<int K>
__global__ __launch_bounds__(256, 4)
void lstm_mfma_kernel(const _Float16* __restrict__ Ah,                                  // [NROWS][K]
                      const _Float16* __restrict__ Wh, const _Float16* __restrict__ Wl, // [768][K]
                      const float* __restrict__ bsum,                                   // [768]
                      _Float16* __restrict__ Oh)                                        // [NROWS][256]
{
    __shared__ __align__(16) _Float16 sA[2][64 * 64];    // 8KB each
    __shared__ __align__(16) _Float16 sW[2][96 * 64];    // 12KB each

    const int t    = threadIdx.x;
    const int lane = t & 63;
    const int wave = t >> 6;
    const int wm   = wave >> 1;
    const int wn   = wave & 1;
    const int lrow = lane & 15;
    const int lkb  = lane >> 4;

    const int bid = blockIdx.x;
    const int xc  = bid & 7, q = bid >> 3;
    const int n0  = (q & 7) * 32;
    const int m0  = (xc + ((q >> 3) << 3)) * 128;
    constexpr int NT = K / 32;

    f32x4 acc[3][4];
#pragma unroll
    for (int g = 0; g < 3; ++g)
#pragma unroll
        for (int fm = 0; fm < 4; ++fm) acc[g][fm] = (f32x4)0.f;

    auto stage = [&](int bi, int kt) {
        const int k0 = kt * 32;
#pragma unroll
        for (int i = 0; i < 2; ++i) {                 // A: 512 chunks
            int idx = i * 256 + t;
            int line = idx >> 3, p = idx & 7;
            int c = p ^ (line & 7);
            int row = 2 * line + (c >> 2);
            gld16(Ah + (size_t)(m0 + row) * K + k0 + (c & 3) * 8, &sA[bi][idx * 8]);
        }
#pragma unroll
        for (int i = 0; i < 3; ++i) {                 // W: 768 chunks (hi/lo paired)
            int idx = i * 256 + t;
            int line = idx >> 3, p = idx & 7;
            int c = p ^ (line & 7);
            int grow = (line >> 5) * 256 + n0 + (line & 31);
            const _Float16* base = (c & 4) ? Wl : Wh;
            gld16(base + (size_t)grow * K + k0 + (c & 3) * 8, &sW[bi][idx * 8]);
        }
    };

    auto compute = [&](int bi) {
        half8 xh[4];
#pragma unroll
        for (int fm = 0; fm < 4; ++fm) {
            int r = wm * 64 + fm * 16 + lrow;
            int line = r >> 1;
            int c = ((r & 1) << 2) | lkb;
            xh[fm] = *(const half8*)(&sA[bi][line * 64 + ((c ^ (line & 7)) << 3)]);
        }
        half8 wwh[3], wwl[3];
#pragma unroll
        for (int g = 0; g < 3; ++g) {
            int wr = g * 32 + wn * 16 + lrow;
            int rb = wr * 64;
            wwh[g] = *(const half8*)(&sW[bi][rb + ((lkb       ^ (wr & 7)) << 3)]);
            wwl[g] = *(const half8*)(&sW[bi][rb + (((4 | lkb) ^ (wr & 7)) << 3)]);
        }
        __builtin_amdgcn_s_setprio(1);
#pragma unroll
        for (int g = 0; g < 3; ++g)
#pragma unroll
            for (int fm = 0; fm < 4; ++fm) {
                acc[g][fm] = __builtin_amdgcn_mfma_f32_16x16x32_f16(wwh[g], xh[fm], acc[g][fm], 0, 0, 0);
                acc[g][fm] = __builtin_amdgcn_mfma_f32_16x16x32_f16(wwl[g], xh[fm], acc[g][fm], 0, 0, 0);
            }
        __builtin_amdgcn_s_setprio(0);
    };

    stage(0, 0);
    stage(1, 1);                       // 10 loads/thread in flight
    for (int kt = 0; kt < NT; ++kt) {
        if (kt < NT - 1) { VMW(5); }   // tile kt landed; tile kt+1 still in flight
        else             { VMW(0); }
        BAR();
        SCHED0;
        compute(kt & 1);
        LGKM0;
        BAR();
        SCHED0;
        if (kt + 2 < NT) stage(kt & 1, kt + 2);
    }

    // epilogue: n = n0 + wn*16 + lkb*4 + j ; m = m0 + wm*64 + fm*16 + lrow
    const int nbase = n0 + wn * 16 + lkb * 4;
    const f32x4 bI = *(const f32x4*)(bsum + nbase);
    const f32x4 bG = *(const f32x4*)(bsum + 256 + nbase);
    const f32x4 bO = *(const f32x4*)(bsum + 512 + nbase);

#pragma unroll
    for (int fm = 0; fm < 4; ++fm) {
        const int m = m0 + wm * 64 + fm * 16 + lrow;
        half4v oh;
#pragma unroll
        for (int j = 0; j < 4; ++j) {
            float gi = acc[0][fm][j] + bI[j];
            float gg = acc[1][fm][j] + bG[j];
            float go = acc[2][fm][j] + bO[j];
            float c2 = fsig(gi) * ftanh(gg);
            oh[j] = (_Float16)(fsig(go) * ftanh(c2));
        }
        *(half4v*)(Oh + (size_t)m * HSZ + nbase) = oh;
    }
}

// ---------------- FC (MFMA, 2-pass) + fused tanh-softmax-normalize ----------------

__global__ __launch_bounds__(256)
void fc_softmax_kernel(const _Float16* __restrict__ hhi,
                       const float* __restrict__ fcW, const float* __restrict__ fcb,
                       float* __restrict__ out)
{
    __shared__ __align__(16) _Float16 sWh[64 * 256];   // 32KB
    __shared__ __align__(16) _Float16 sWl[64 * 256];   // 32KB
    __shared__ __align__(16) _Float16 sH[2][32 * 64];  // 4KB each (row-paired lines)

    const int t    = threadIdx.x;
    const int lane = t & 63;
    const int wave = t >> 6;
    const int ln   = lane & 15;
    const int lkb  = lane >> 4;

    const int bid = blockIdx.x;
    // f/2 == bid (mod 8) -> same XCD as the layer-3 writer of these rows
    const int f   = (((bid & 7) << 1) | ((bid >> 3) & 1)) | ((bid >> 4) << 4);
    const int m0  = f * 64;

    auto stageH = [&](int bi, int kt) {               // 256 chunks: 1/thread
        int idx = t;
        int line = idx >> 3, p = idx & 7;
        int c = p ^ (line & 7);
        int row = 2 * line + (c >> 2);
        gld16(hhi + (size_t)(m0 + row) * 256 + kt * 32 + (c & 3) * 8, &sH[bi][idx * 8]);
    };

    stageH(0, 0);
    stageH(1, 1);

    // convert fcW (64x256 f32) -> hi/lo fp16 LDS, 16B-chunk XOR swizzle
#pragma unroll
    for (int i = 0; i < 8; ++i) {
        int idx = i * 256 + t;            // 0..2047
        int row = idx >> 5, c = idx & 31; // chunk = 8 k
        const float* src = fcW + (size_t)row * 256 + c * 8;
        f32x4 v0 = *(const f32x4*)src;
        f32x4 v1 = *(const f32x4*)(src + 4);
        half8 h, l;
#pragma unroll
        for (int j = 0; j < 4; ++j) {
            _Float16 h0 = (_Float16)v0[j]; h[j]     = h0; l[j]     = (_Float16)(v0[j] - (float)h0);
            _Float16 h1 = (_Float16)v1[j]; h[4 + j] = h1; l[4 + j] = (_Float16)(v1[j] - (float)h1);
        }
        int off = row * 256 + ((c ^ (row & 7)) << 3);
        *(half8*)(sWh + off) = h;
        *(half8*)(sWl + off) = l;
    }

    f32x4 acc[4];
#pragma unroll
    for (int nf = 0; nf < 4; ++nf) acc[nf] = (f32x4)0.f;

    auto computeF = [&](int bi, int kt) {
        const int r = wave * 16 + ln;
        const int line = r >> 1;
        const int hc = ((r & 1) << 2) | lkb;
        half8 ah = *(const half8*)(&sH[bi][line * 64 + ((hc ^ (line & 7)) << 3)]);
        __builtin_amdgcn_s_setprio(1);
#pragma unroll
        for (int nf = 0; nf < 4; ++nf) {
            int wr  = nf * 16 + ln;
            int ch  = kt * 4 + lkb;
            int off = wr * 256 + ((ch ^ (wr & 7)) << 3);
            half8 wwh = *(const half8*)(&sWh[off]);
            half8 wwl = *(const half8*)(&sWl[off]);
            acc[nf] = __builtin_amdgcn_mfma_f32_16x16x32_f16(ah, wwh, acc[nf], 0, 0, 0);
            acc[nf] = __builtin_amdgcn_mfma_f32_16x16x32_f16(ah, wwl, acc[nf], 0, 0, 0);
        }
        __builtin_amdgcn_s_setprio(0);
    };

    __syncthreads();   // one-time: drains fcW ds_writes + prologue stages (vmcnt 0)

    for (int kt = 0; kt < 8; ++kt) {
        if (kt >= 2) {                    // tiles 0,1 covered by syncthreads
            if (kt < 7) { VMW(1); }       // tile kt landed; kt+1 in flight
            else        { VMW(0); }
        }
        BAR();
        SCHED0;
        computeF(kt & 1, kt);
        LGKM0;
        BAR();
        SCHED0;
        if (kt + 2 < 8) stageH(kt & 1, kt + 2);
    }

    // ---- epilogue: bias + tanh-softmax-normalize over n (64) per row ----
    float fb[4];
#pragma unroll
    for (int nf = 0; nf < 4; ++nf) fb[nf] = fcb[nf * 16 + ln];

    float tt[4][4], aa[4][4];
#pragma unroll
    for (int nf = 0; nf < 4; ++nf)
#pragma unroll
        for (int r = 0; r < 4; ++r) {
            float o = acc[nf][r] + fb[nf];
            tt[nf][r] = ftanh(o);
            aa[nf][r] = fabsf(o);
        }

    float mx[4];
#pragma unroll
    for (int r = 0; r < 4; ++r)
        mx[r] = fmaxf(fmaxf(aa[0][r], aa[1][r]), fmaxf(aa[2][r], aa[3][r]));
#pragma unroll
    for (int ofs = 1; ofs < 16; ofs <<= 1)
#pragma unroll
        for (int r = 0; r < 4; ++r) mx[r] = fmaxf(mx[r], __shfl_xor(mx[r], ofs, 64));

    float ee[4][4], Z[4];
#pragma unroll
    for (int r = 0; r < 4; ++r) Z[r] = 0.f;
#pragma unroll
    for (int nf = 0; nf < 4; ++nf)
#pragma unroll
        for (int r = 0; r < 4; ++r) { ee[nf][r] = __expf(aa[nf][r] - mx[r]); Z[r] += ee[nf][r]; }
#pragma unroll
    for (int ofs = 1; ofs < 16; ofs <<= 1)
#pragma unroll
        for (int r = 0; r < 4; ++r) Z[r] += __shfl_xor(Z[r], ofs, 64);

    float w[4][4], S[4];
#pragma unroll
    for (int r = 0; r < 4; ++r) S[r] = 0.f;
#pragma unroll
    for (int nf = 0; nf < 4; ++nf)
#pragma unroll
        for (int r = 0; r < 4; ++r) { w[nf][r] = tt[nf][r] * ee[nf][r] / Z[r]; S[r] += fabsf(w[nf][r]); }
#pragma unroll
    for (int ofs = 1; ofs < 16; ofs <<= 1)
#pragma unroll
        for (int r = 0; r < 4; ++r) S[r] += __shfl_xor(S[r], ofs, 64);

#pragma unroll
    for (int r = 0; r < 4; ++r) {
        const float inv = 1.f / fmaxf(S[r], 1e-12f);
        const int m = m0 + wave * 16 + lkb * 4 + r;
#pragma unroll
        for (int nf = 0; nf < 4; ++nf)
            out[(size_t)m * 64 + nf * 16 + ln] = w[nf][r] * inv;
    }
}

// ---------------- launch ----------------

extern "C" void kernel_launch(void* const* d_in, const int* in_sizes, int n_in,
                              void* d_out, int out_size, void* d_ws, size_t ws_size,
                              hipStream_t stream) {
    const float* x    = (const float*)d_in[0];
    const float* Wih0 = (const float*)d_in[1];
    const float* bih0 = (const float*)d_in[3];
    const float* bhh0 = (const float*)d_in[4];
    const float* Wih1 = (const float*)d_in[5];
    const float* bih1 = (const float*)d_in[7];
    const float* bhh1 = (const float*)d_in[8];
    const float* Wih2 = (const float*)d_in[9];
    const float* bih2 = (const float*)d_in[11];
    const float* bhh2 = (const float*)d_in[12];
    const float* fcW  = (const float*)d_in[13];
    const float* fcb  = (const float*)d_in[14];

    char* ws = (char*)d_ws;
    _Float16* hA = (_Float16*)(ws);                    // 8 MB
    _Float16* hB = (_Float16*)(ws + (8u  << 20));      // 8 MB
    _Float16* xh = (_Float16*)(ws + (16u << 20));      // 4 MB

    // W planes + bsums live in d_out (4 MB), fully consumed before fc writes out.
    char* ob = (char*)d_out;
    _Float16* W0h = (_Float16*)(ob);
    _Float16* W0l = (_Float16*)(ob + 196608);
    _Float16* W1h = (_Float16*)(ob + 393216);
    _Float16* W1l = (_Float16*)(ob + 786432);
    _Float16* W2h = (_Float16*)(ob + 1179648);
    _Float16* W2l = (_Float16*)(ob + 1572864);
    float*    bs0 = (float*)(ob + 1966080);
    float*    bs1 = (float*)(ob + 1969152);
    float*    bs2 = (float*)(ob + 1972224);
    float*    outp = (float*)d_out;

    dim3 blk(256);

    prep_all_kernel<<<dim3(PS4 / 256), blk, 0, stream>>>(
        x, Wih0, bih0, bhh0, Wih1, bih1, bhh1, Wih2, bih2, bhh2,
        xh, W0h, W0l, W1h, W1l, W2h, W2l, bs0, bs1, bs2);

    lstm_mfma_kernel<128><<<dim3(1024), blk, 0, stream>>>(xh, W0h, W0l, bs0, hA);
    lstm_mfma_kernel<256><<<dim3(1024), blk, 0, stream>>>(hA, W1h, W1l, bs1, hB);
    lstm_mfma_kernel<256><<<dim3(1024), blk, 0, stream>>>(hB, W2h, W2l, bs2, hA);

    fc_softmax_kernel<<<dim3(256), blk, 0, stream>>>(hA, fcW, fcb, outp);
}